// Round 1
// baseline (6751.723 us; speedup 1.0000x reference)
//
#include <hip/hip_runtime.h>
#include <math.h>

#define NSEQ 320
#define HDIM 512
#define G4   2048
#define EMBD 300
#define ELMOD 1024
#define XDIM 812

__device__ __forceinline__ float sigmoidf_(float x) {
    return 1.0f / (1.0f + expf(-x));
}

// ---------- copy GloVe emb into X[:, 0:300] ----------
__global__ __launch_bounds__(128) void build_emb_kernel(
    const int* __restrict__ tok, const float* __restrict__ w_emb,
    float* __restrict__ X)
{
    int n = blockIdx.x;
    int tid = threadIdx.x;
    if (tid < 75) {   // 300 floats = 75 float4
        const float4* src = (const float4*)(w_emb + (size_t)tok[n] * EMBD);
        float4* dst = (float4*)(X + (size_t)n * XDIM);
        dst[tid] = src[tid];
    }
}

// ---------- generic C[M,N] = gatherA[M,K] * W[N,K]^T + bias ----------
// 64x64 tile, 256 threads, 4x4 micro, fp32
__global__ __launch_bounds__(256) void gemm_bt_kernel(
    const float* __restrict__ A, int lda, const int* __restrict__ gather,
    const float* __restrict__ W, int ldw,
    const float* __restrict__ bias,
    float* __restrict__ C, int ldc,
    int M, int N, int K)
{
    __shared__ float As[16][68];
    __shared__ float Bs[16][68];
    const int m0 = blockIdx.y * 64;
    const int n0 = blockIdx.x * 64;
    const int tid = threadIdx.x;
    const int ty = tid >> 4;
    const int tx = tid & 15;
    const int lrow = tid >> 2;
    const int kq = (tid & 3) << 2;

    const float* arow = A + (size_t)(gather ? gather[m0 + lrow] : (m0 + lrow)) * lda;
    const float* wrow = W + (size_t)(n0 + lrow) * ldw;

    float acc[4][4] = {};

    for (int k0 = 0; k0 < K; k0 += 16) {
        if (k0 + 16 <= K) {
            float4 va = *(const float4*)(arow + k0 + kq);
            As[kq+0][lrow] = va.x; As[kq+1][lrow] = va.y;
            As[kq+2][lrow] = va.z; As[kq+3][lrow] = va.w;
            float4 vb = *(const float4*)(wrow + k0 + kq);
            Bs[kq+0][lrow] = vb.x; Bs[kq+1][lrow] = vb.y;
            Bs[kq+2][lrow] = vb.z; Bs[kq+3][lrow] = vb.w;
        } else {
            #pragma unroll
            for (int q = 0; q < 4; ++q) {
                int k = k0 + kq + q;
                As[kq+q][lrow] = (k < K) ? arow[k] : 0.0f;
                Bs[kq+q][lrow] = (k < K) ? wrow[k] : 0.0f;
            }
        }
        __syncthreads();
        #pragma unroll
        for (int k = 0; k < 16; ++k) {
            float4 av = *(const float4*)&As[k][ty << 2];
            float4 bv = *(const float4*)&Bs[k][tx << 2];
            acc[0][0] += av.x*bv.x; acc[0][1] += av.x*bv.y; acc[0][2] += av.x*bv.z; acc[0][3] += av.x*bv.w;
            acc[1][0] += av.y*bv.x; acc[1][1] += av.y*bv.y; acc[1][2] += av.y*bv.z; acc[1][3] += av.y*bv.w;
            acc[2][0] += av.z*bv.x; acc[2][1] += av.z*bv.y; acc[2][2] += av.z*bv.z; acc[2][3] += av.z*bv.w;
            acc[3][0] += av.w*bv.x; acc[3][1] += av.w*bv.y; acc[3][2] += av.w*bv.z; acc[3][3] += av.w*bv.w;
        }
        __syncthreads();
    }
    float4 bv = *(const float4*)(bias + n0 + (tx << 2));
    #pragma unroll
    for (int i = 0; i < 4; ++i) {
        size_t m = (size_t)m0 + (ty << 2) + i;
        float4 v;
        v.x = acc[i][0] + bv.x; v.y = acc[i][1] + bv.y;
        v.z = acc[i][2] + bv.z; v.w = acc[i][3] + bv.w;
        *(float4*)(C + m * ldc + n0 + (tx << 2)) = v;
    }
}

// ---------- fused LSTM step: gates = XP[:,t] + h_in @ Whh^T, then pointwise ----------
// tile 32 (n) x 32 (j), 4 gates per (n,j); 256 threads, micro 2x2
__global__ __launch_bounds__(256) void lstm_step_kernel(
    const float* __restrict__ XP,     // [Ntok][2048], row = n*T + t
    const float* __restrict__ Whh,    // [2048][512] row-major
    const float* __restrict__ h_in,   // [320][512]
    float* __restrict__ h_out,        // [320][512]
    float* __restrict__ c_state,      // [320][512]
    float* __restrict__ h_seq,        // layer0: [Ntok][512] (row n*T+t) or null
    float* __restrict__ h_last,       // layer1: [320][512] or null
    const int* __restrict__ lens,
    int t, int T)
{
    __shared__ float As[16][34];
    __shared__ float Bs[4][16][34];
    const int n0 = blockIdx.y * 32;
    const int j0 = blockIdx.x * 32;
    const int tid = threadIdx.x;
    const int ty = tid >> 4;
    const int tx = tid & 15;

    float acc[4][2][2] = {};

    const int an  = tid >> 3;          // 0..31  (n within tile)
    const int akq = (tid & 7) << 1;    // k pair
    const int rr  = tid >> 1;          // 0..127
    const int bg  = rr >> 5;           // gate
    const int bj  = rr & 31;           // j within tile
    const int bkq = (tid & 1) << 3;    // k block of 8
    const float* hrow = h_in + (size_t)(n0 + an) * HDIM + akq;
    const float* wrow = Whh + (size_t)(bg * HDIM + j0 + bj) * HDIM + bkq;

    for (int k0 = 0; k0 < HDIM; k0 += 16) {
        float2 va = *(const float2*)(hrow + k0);
        As[akq+0][an] = va.x; As[akq+1][an] = va.y;
        float4 v0 = *(const float4*)(wrow + k0);
        float4 v1 = *(const float4*)(wrow + k0 + 4);
        Bs[bg][bkq+0][bj] = v0.x; Bs[bg][bkq+1][bj] = v0.y;
        Bs[bg][bkq+2][bj] = v0.z; Bs[bg][bkq+3][bj] = v0.w;
        Bs[bg][bkq+4][bj] = v1.x; Bs[bg][bkq+5][bj] = v1.y;
        Bs[bg][bkq+6][bj] = v1.z; Bs[bg][bkq+7][bj] = v1.w;
        __syncthreads();
        #pragma unroll
        for (int k = 0; k < 16; ++k) {
            float a0 = As[k][ty*2+0];
            float a1 = As[k][ty*2+1];
            #pragma unroll
            for (int g = 0; g < 4; ++g) {
                float b0 = Bs[g][k][tx*2+0];
                float b1 = Bs[g][k][tx*2+1];
                acc[g][0][0] += a0 * b0;
                acc[g][0][1] += a0 * b1;
                acc[g][1][0] += a1 * b0;
                acc[g][1][1] += a1 * b1;
            }
        }
        __syncthreads();
    }

    #pragma unroll
    for (int ni = 0; ni < 2; ++ni) {
        const int n = n0 + ty*2 + ni;
        const float* xp = XP + ((size_t)n * T + t) * G4;
        #pragma unroll
        for (int ji = 0; ji < 2; ++ji) {
            const int j = j0 + tx*2 + ji;
            float gi = acc[0][ni][ji] + xp[j];
            float gf = acc[1][ni][ji] + xp[HDIM + j];
            float gg = acc[2][ni][ji] + xp[2*HDIM + j];
            float go = acc[3][ni][ji] + xp[3*HDIM + j];
            size_t idx = (size_t)n * HDIM + j;
            float c = c_state[idx];
            c = sigmoidf_(gf) * c + sigmoidf_(gi) * tanhf(gg);
            float h = sigmoidf_(go) * tanhf(c);
            c_state[idx] = c;
            h_out[idx] = h;
            if (h_seq)  h_seq[((size_t)n * T + t) * HDIM + j] = h;
            if (h_last && (lens[n] - 1 == t)) h_last[idx] = h;
        }
    }
}

// ---------- nz flags: row has any nonzero ----------
__global__ __launch_bounds__(64) void nz_kernel(
    const float* __restrict__ he, int* __restrict__ nz)
{
    int r = blockIdx.x;
    int lane = threadIdx.x;
    const float* row = he + (size_t)r * HDIM;
    bool any = false;
    for (int k = lane; k < HDIM; k += 64) any |= (row[k] != 0.0f);
    unsigned long long b = __ballot(any);
    if (lane == 0) nz[r] = (b != 0ull) ? 1 : 0;
}

// ---------- text_rel expansion: out[b,i,j,k,0:512]=he[b,j]*m1, [512:1024]=he[b,k]*m2 ----------
__global__ __launch_bounds__(256) void expand_kernel(
    const float* __restrict__ he, const int* __restrict__ nz,
    float* __restrict__ out)
{
    int blk = blockIdx.x;               // ((b*10+i)*10+j)*10+k
    int k = blk % 10;
    int j = (blk / 10) % 10;
    int i = (blk / 100) % 10;
    int b = blk / 1000;
    int tid = threadIdx.x;
    float4* o = (float4*)(out + (size_t)blk * 1024);
    float4 z; z.x = z.y = z.z = z.w = 0.0f;
    if (tid < 128) {
        // t_rel: he[b,j] * (j<=i) * ((k<=i) && nz[b,k])
        bool m = (j <= i) && (k <= i) && (nz[b*10 + k] != 0);
        float4 v = m ? ((const float4*)(he + (size_t)(b*10 + j) * HDIM))[tid] : z;
        o[tid] = v;
    } else {
        int c = tid - 128;
        // tmp: he[b,k] * (k<=i) * ((j<=i) && nz[b,j])
        bool m = (k <= i) && (j <= i) && (nz[b*10 + j] != 0);
        float4 v = m ? ((const float4*)(he + (size_t)(b*10 + k) * HDIM))[c] : z;
        o[128 + c] = v;
    }
}

extern "C" void kernel_launch(void* const* d_in, const int* in_sizes, int n_in,
                              void* d_out, int out_size, void* d_ws, size_t ws_size,
                              hipStream_t stream)
{
    (void)in_sizes; (void)n_in; (void)out_size; (void)ws_size;
    const int* ques     = (const int*)d_in[0];
    const int* hist     = (const int*)d_in[1];
    const int* ques_len = (const int*)d_in[2];
    const int* hist_len = (const int*)d_in[3];
    const float* w_emb  = (const float*)d_in[6];
    const float* elmo   = (const float*)d_in[7];
    const float* Wc     = (const float*)d_in[8];
    const float* bc     = (const float*)d_in[9];

    float* ws = (float*)d_ws;
    size_t off = 0;
    float* X   = ws + off; off += (size_t)12800 * XDIM;   // 10.39M
    float* XP  = ws + off; off += (size_t)12800 * G4;     // 26.21M
    float* H1s = ws + off; off += (size_t)12800 * HDIM;   // 6.55M
    float* hb0 = ws + off; off += (size_t)NSEQ * HDIM;
    float* hb1 = ws + off; off += (size_t)NSEQ * HDIM;
    float* cst = ws + off; off += (size_t)NSEQ * HDIM;
    float* he  = ws + off; off += (size_t)NSEQ * HDIM;
    int*   nzb = (int*)(ws + off);

    float* out = (float*)d_out;
    float* ques_embed = out;                       // [320][512]
    float* text_rel   = out + (size_t)NSEQ * HDIM; // [32000][1024]

    for (int s = 0; s < 2; ++s) {
        const int* tok  = s ? hist : ques;
        const int* lens = s ? hist_len : ques_len;
        int T = s ? 40 : 20;
        int Ntok = NSEQ * T;
        const float* Wih0 = (const float*)d_in[10 + 6*s];
        const float* Whh0 = (const float*)d_in[11 + 6*s];
        const float* b0   = (const float*)d_in[12 + 6*s];
        const float* Wih1 = (const float*)d_in[13 + 6*s];
        const float* Whh1 = (const float*)d_in[14 + 6*s];
        const float* b1   = (const float*)d_in[15 + 6*s];
        float* hlast = s ? he : ques_embed;

        // X[:, 0:300] = w_emb[tok]
        build_emb_kernel<<<Ntok, 128, 0, stream>>>(tok, w_emb, X);
        // X[:, 300:812] = elmo[tok] @ Wc^T + bc
        gemm_bt_kernel<<<dim3(HDIM/64, Ntok/64), 256, 0, stream>>>(
            elmo, ELMOD, tok, Wc, ELMOD, bc, X + EMBD, XDIM, Ntok, HDIM, ELMOD);
        // XP = X @ Wih0^T + b0
        gemm_bt_kernel<<<dim3(G4/64, Ntok/64), 256, 0, stream>>>(
            X, XDIM, nullptr, Wih0, XDIM, b0, XP, G4, Ntok, G4, XDIM);

        hipMemsetAsync(hb0, 0, (size_t)NSEQ*HDIM*sizeof(float), stream);
        hipMemsetAsync(cst, 0, (size_t)NSEQ*HDIM*sizeof(float), stream);
        dim3 gs(HDIM/32, NSEQ/32);
        for (int t = 0; t < T; ++t) {
            float* hin  = (t & 1) ? hb1 : hb0;
            float* hout = (t & 1) ? hb0 : hb1;
            lstm_step_kernel<<<gs, 256, 0, stream>>>(
                XP, Whh0, hin, hout, cst, H1s, nullptr, lens, t, T);
        }
        // XP = H1 @ Wih1^T + b1
        gemm_bt_kernel<<<dim3(G4/64, Ntok/64), 256, 0, stream>>>(
            H1s, HDIM, nullptr, Wih1, HDIM, b1, XP, G4, Ntok, G4, HDIM);
        hipMemsetAsync(hb0, 0, (size_t)NSEQ*HDIM*sizeof(float), stream);
        hipMemsetAsync(cst, 0, (size_t)NSEQ*HDIM*sizeof(float), stream);
        for (int t = 0; t < T; ++t) {
            float* hin  = (t & 1) ? hb1 : hb0;
            float* hout = (t & 1) ? hb0 : hb1;
            lstm_step_kernel<<<gs, 256, 0, stream>>>(
                XP, Whh1, hin, hout, cst, nullptr, hlast, lens, t, T);
        }
    }

    nz_kernel<<<NSEQ, 64, 0, stream>>>(he, nzb);
    expand_kernel<<<32000, 256, 0, stream>>>(he, nzb, text_rel);
}

// Round 2
// 1192.308 us; speedup vs baseline: 5.6627x; 5.6627x over previous
//
#include <hip/hip_runtime.h>
#include <math.h>

#define NSEQ 320
#define HDIM 512
#define G4   2048
#define EMBD 300
#define ELMOD 1024
#define XPAD 832          // 812 padded to multiple of 32

typedef __attribute__((ext_vector_type(8))) short bf16x8;
typedef __attribute__((ext_vector_type(4))) float f32x4;
typedef unsigned short ushort_t;

__device__ __forceinline__ float sigmoidf_(float x) { return 1.0f / (1.0f + expf(-x)); }

__device__ __forceinline__ ushort_t f2bf(float f) {
    unsigned u = __float_as_uint(f);
    u = (u + 0x7FFFu + ((u >> 16) & 1u)) >> 16;   // RNE
    return (ushort_t)u;
}
__device__ __forceinline__ float bf2f(ushort_t u) {
    return __uint_as_float(((unsigned)u) << 16);
}
__device__ __forceinline__ unsigned pack2(float a, float b) {
    return (unsigned)f2bf(a) | ((unsigned)f2bf(b) << 16);
}

// ---------------- fp32 -> bf16 weight conversion (with zero pad / offset) ----------------
__global__ __launch_bounds__(256) void conv_bf16_kernel(
    const float* __restrict__ src, int srcCols,
    ushort_t* __restrict__ dst, int dstStride, int dstOff,
    int fillCols)
{
    int c = blockIdx.x * 256 + threadIdx.x;
    int r = blockIdx.y;
    if (c >= fillCols) return;
    float v = (c < srcCols) ? src[(size_t)r * srcCols + c] : 0.0f;
    dst[(size_t)r * dstStride + dstOff + c] = f2bf(v);
}

// ---------------- GloVe gather -> Xb[:,0:300] bf16, zero pad cols [812,832) ----------------
__global__ __launch_bounds__(128) void emb_gather_kernel(
    const int* __restrict__ tok, const float* __restrict__ w_emb,
    ushort_t* __restrict__ Xb)
{
    int n = blockIdx.x;
    int t = threadIdx.x;
    ushort_t* dst = Xb + (size_t)n * XPAD;
    if (t < 75) {
        const float4* src = (const float4*)(w_emb + (size_t)tok[n] * EMBD);
        float4 v = src[t];
        dst[4*t+0] = f2bf(v.x); dst[4*t+1] = f2bf(v.y);
        dst[4*t+2] = f2bf(v.z); dst[4*t+3] = f2bf(v.w);
    } else if (t >= 108) {  // 20 pad cols
        dst[812 + (t - 108)] = 0;
    }
}

// ---------------- feed-forward GEMM: C_bf16[M][N] = A[M][K] * W[N][K]^T + bias ----------------
// A: bf16 (Ab, strideA) OR fp32 gather (Af + tok[m]*strideA). 64x64 tile, 4 waves, K%32==0.
__global__ __launch_bounds__(256) void gemm_ff_kernel(
    const ushort_t* __restrict__ Ab, const float* __restrict__ Af,
    const int* __restrict__ tok, int strideA,
    const ushort_t* __restrict__ W, const float* __restrict__ bias,
    ushort_t* __restrict__ C, int strideC, int K)
{
    __shared__ ushort_t As[64 * 40];
    __shared__ ushort_t Bs[64 * 40];
    const int m0 = blockIdx.y * 64;
    const int n0 = blockIdx.x * 64;
    const int tid = threadIdx.x;
    const int r  = tid >> 2;
    const int kq = (tid & 3) << 3;

    const ushort_t* arow_b = nullptr;
    const float*    arow_f = nullptr;
    if (Af) arow_f = Af + (size_t)tok[m0 + r] * strideA + kq;
    else    arow_b = Ab + (size_t)(m0 + r) * strideA + kq;
    const ushort_t* brow = W + (size_t)(n0 + r) * K + kq;

    const int lane = tid & 63;
    const int w = tid >> 6;
    const int wm = w & 1, wn = w >> 1;
    const int kc = (lane >> 4) << 3;

    f32x4 acc[2][2];
    #pragma unroll
    for (int f = 0; f < 2; ++f)
        #pragma unroll
        for (int g = 0; g < 2; ++g)
            acc[f][g] = (f32x4){0.f, 0.f, 0.f, 0.f};

    for (int k0 = 0; k0 < K; k0 += 32) {
        if (Af) {
            float4 v0 = ((const float4*)(arow_f + k0))[0];
            float4 v1 = ((const float4*)(arow_f + k0))[1];
            uint4 p; p.x = pack2(v0.x, v0.y); p.y = pack2(v0.z, v0.w);
            p.z = pack2(v1.x, v1.y); p.w = pack2(v1.z, v1.w);
            *(uint4*)&As[r*40 + kq] = p;
        } else {
            *(uint4*)&As[r*40 + kq] = *(const uint4*)(arow_b + k0);
        }
        *(uint4*)&Bs[r*40 + kq] = *(const uint4*)(brow + k0);
        __syncthreads();
        bf16x8 af[2], bfr[2];
        #pragma unroll
        for (int f = 0; f < 2; ++f)
            af[f] = *(const bf16x8*)&As[(wm*32 + f*16 + (lane & 15))*40 + kc];
        #pragma unroll
        for (int g = 0; g < 2; ++g)
            bfr[g] = *(const bf16x8*)&Bs[(wn*32 + g*16 + (lane & 15))*40 + kc];
        #pragma unroll
        for (int f = 0; f < 2; ++f)
            #pragma unroll
            for (int g = 0; g < 2; ++g)
                acc[f][g] = __builtin_amdgcn_mfma_f32_16x16x32_bf16(af[f], bfr[g], acc[f][g], 0, 0, 0);
        __syncthreads();
    }

    #pragma unroll
    for (int f = 0; f < 2; ++f) {
        #pragma unroll
        for (int g = 0; g < 2; ++g) {
            int col = n0 + wn*32 + g*16 + (lane & 15);
            float bv = bias[col];
            #pragma unroll
            for (int i = 0; i < 4; ++i) {
                int row = m0 + wm*32 + f*16 + ((lane >> 4) << 2) + i;
                C[(size_t)row * strideC + col] = f2bf(acc[f][g][i] + bv);
            }
        }
    }
}

// ---------------- LSTM superstep: fused gates GEMM + pointwise, up to 4 cells ----------------
struct Cell {
    const ushort_t* A;      // [320][K] bf16
    const ushort_t* B;      // [2048][K] bf16, rows = gate*512 + j
    const ushort_t* xp;     // L0: XP0bf + (rowoff + t)*2048 ; row stride per n = T*2048
    const float* bias;      // L1: b1
    float* c;               // [320][512] fp32
    ushort_t* hA;           // bf16 h out, [n*strideHA + j]
    ushort_t* hB;           // optional second bf16 dest [n*1024 + j]
    float* hlast;           // optional fp32 [n*512 + j] when lens[n]-1==t
    const int* lens;
    int t, K, strideHA, xpRowStride;
};
struct CellPack { Cell cells[4]; };

__global__ __launch_bounds__(256) void lstm_superstep_kernel(CellPack P)
{
    const Cell cl = P.cells[blockIdx.z];
    const int j0 = blockIdx.x * 16;      // hidden j tile (512/16 = 32 tiles)
    const int n0 = blockIdx.y * 64;      // sequence tile (320/64 = 5)
    __shared__ ushort_t As[64 * 40];
    __shared__ ushort_t Bs[64 * 40];
    __shared__ float Gt[64][68];

    const int tid = threadIdx.x;
    const int r  = tid >> 2;
    const int kq = (tid & 3) << 3;
    const int K = cl.K;

    const ushort_t* arow = cl.A + (size_t)(n0 + r) * K + kq;
    const ushort_t* brow = cl.B + (size_t)((r >> 4) * HDIM + j0 + (r & 15)) * K + kq;

    const int lane = tid & 63;
    const int w = tid >> 6;
    const int wm = w & 1, wn = w >> 1;
    const int kc = (lane >> 4) << 3;

    f32x4 acc[2][2];
    #pragma unroll
    for (int f = 0; f < 2; ++f)
        #pragma unroll
        for (int g = 0; g < 2; ++g)
            acc[f][g] = (f32x4){0.f, 0.f, 0.f, 0.f};

    for (int k0 = 0; k0 < K; k0 += 32) {
        *(uint4*)&As[r*40 + kq] = *(const uint4*)(arow + k0);
        *(uint4*)&Bs[r*40 + kq] = *(const uint4*)(brow + k0);
        __syncthreads();
        bf16x8 af[2], bfr[2];
        #pragma unroll
        for (int f = 0; f < 2; ++f)
            af[f] = *(const bf16x8*)&As[(wm*32 + f*16 + (lane & 15))*40 + kc];
        #pragma unroll
        for (int g = 0; g < 2; ++g)
            bfr[g] = *(const bf16x8*)&Bs[(wn*32 + g*16 + (lane & 15))*40 + kc];
        #pragma unroll
        for (int f = 0; f < 2; ++f)
            #pragma unroll
            for (int g = 0; g < 2; ++g)
                acc[f][g] = __builtin_amdgcn_mfma_f32_16x16x32_bf16(af[f], bfr[g], acc[f][g], 0, 0, 0);
        __syncthreads();
    }

    // dump gates to LDS: tile col = gate*16 + jj
    #pragma unroll
    for (int f = 0; f < 2; ++f)
        #pragma unroll
        for (int g = 0; g < 2; ++g)
            #pragma unroll
            for (int i = 0; i < 4; ++i)
                Gt[wm*32 + f*16 + ((lane >> 4) << 2) + i][wn*32 + g*16 + (lane & 15)] = acc[f][g][i];
    __syncthreads();

    // pointwise: 1024 (n,j) pairs, 4 per thread
    #pragma unroll
    for (int q = 0; q < 4; ++q) {
        int p = tid + q * 256;
        int nl = p >> 4, jj = p & 15;
        int n = n0 + nl, j = j0 + jj;
        float gi = Gt[nl][jj],      gf = Gt[nl][16 + jj];
        float gg = Gt[nl][32 + jj], go = Gt[nl][48 + jj];
        if (cl.xp) {
            const ushort_t* xr = cl.xp + (size_t)n * cl.xpRowStride;
            gi += bf2f(xr[j]);          gf += bf2f(xr[HDIM + j]);
            gg += bf2f(xr[2*HDIM + j]); go += bf2f(xr[3*HDIM + j]);
        } else {
            gi += cl.bias[j];          gf += cl.bias[HDIM + j];
            gg += cl.bias[2*HDIM + j]; go += cl.bias[3*HDIM + j];
        }
        size_t ix = (size_t)n * HDIM + j;
        float c = cl.c[ix];
        c = sigmoidf_(gf) * c + sigmoidf_(gi) * tanhf(gg);
        float h = sigmoidf_(go) * tanhf(c);
        cl.c[ix] = c;
        cl.hA[(size_t)n * cl.strideHA + j] = f2bf(h);
        if (cl.hB) cl.hB[(size_t)n * 1024 + j] = f2bf(h);
        if (cl.hlast && (cl.lens[n] - 1 == cl.t)) cl.hlast[ix] = h;
    }
}

// ---------------- nz flags ----------------
__global__ __launch_bounds__(64) void nz_kernel(
    const float* __restrict__ he, int* __restrict__ nz)
{
    int rr = blockIdx.x;
    int lane = threadIdx.x;
    const float* row = he + (size_t)rr * HDIM;
    bool any = false;
    for (int k = lane; k < HDIM; k += 64) any |= (row[k] != 0.0f);
    unsigned long long b = __ballot(any);
    if (lane == 0) nz[rr] = (b != 0ull) ? 1 : 0;
}

// ---------------- text_rel expansion ----------------
__global__ __launch_bounds__(256) void expand_kernel(
    const float* __restrict__ he, const int* __restrict__ nz,
    float* __restrict__ out)
{
    int blk = blockIdx.x;               // ((b*10+i)*10+j)*10+k
    int k = blk % 10;
    int j = (blk / 10) % 10;
    int i = (blk / 100) % 10;
    int b = blk / 1000;
    int tid = threadIdx.x;
    float4* o = (float4*)(out + (size_t)blk * 1024);
    float4 z; z.x = z.y = z.z = z.w = 0.0f;
    if (tid < 128) {
        bool m = (j <= i) && (k <= i) && (nz[b*10 + k] != 0);
        float4 v = m ? ((const float4*)(he + (size_t)(b*10 + j) * HDIM))[tid] : z;
        o[tid] = v;
    } else {
        int c = tid - 128;
        bool m = (k <= i) && (j <= i) && (nz[b*10 + j] != 0);
        float4 v = m ? ((const float4*)(he + (size_t)(b*10 + k) * HDIM))[c] : z;
        o[128 + c] = v;
    }
}

extern "C" void kernel_launch(void* const* d_in, const int* in_sizes, int n_in,
                              void* d_out, int out_size, void* d_ws, size_t ws_size,
                              hipStream_t stream)
{
    (void)in_sizes; (void)n_in; (void)out_size; (void)ws_size;
    const int* ques     = (const int*)d_in[0];
    const int* hist     = (const int*)d_in[1];
    const int* ques_len = (const int*)d_in[2];
    const int* hist_len = (const int*)d_in[3];
    const float* w_emb  = (const float*)d_in[6];
    const float* elmo   = (const float*)d_in[7];
    const float* Wc     = (const float*)d_in[8];
    const float* bc     = (const float*)d_in[9];

    // ---- workspace layout (bytes) ----
    char* ws = (char*)d_ws;
    size_t off = 0;
    auto alloc = [&](size_t bytes) { char* p = ws + off; off += (bytes + 15) & ~(size_t)15; return p; };
    ushort_t* XP0bf   = (ushort_t*)alloc((size_t)19200 * G4 * 2);      // 78.6 MB
    ushort_t* Xb      = (ushort_t*)alloc((size_t)19200 * XPAD * 2);    // 32.0 MB
    ushort_t* Wcb     = (ushort_t*)alloc((size_t)HDIM * ELMOD * 2);
    ushort_t* Wih0b[2], *Whh0b[2], *Wcat[2];
    for (int s = 0; s < 2; ++s) {
        Wih0b[s] = (ushort_t*)alloc((size_t)G4 * XPAD * 2);
        Whh0b[s] = (ushort_t*)alloc((size_t)G4 * HDIM * 2);
        Wcat[s]  = (ushort_t*)alloc((size_t)G4 * ELMOD * 2);
    }
    char* state_base = ws + off;
    ushort_t* h0buf[2][2];   // [set][parity]
    ushort_t* acat[2][2];
    float* cbuf[2][2];       // [set][layer]
    for (int s = 0; s < 2; ++s)
        for (int p = 0; p < 2; ++p) h0buf[s][p] = (ushort_t*)alloc((size_t)NSEQ * HDIM * 2);
    for (int s = 0; s < 2; ++s)
        for (int p = 0; p < 2; ++p) acat[s][p] = (ushort_t*)alloc((size_t)NSEQ * ELMOD * 2);
    for (int s = 0; s < 2; ++s)
        for (int l = 0; l < 2; ++l) cbuf[s][l] = (float*)alloc((size_t)NSEQ * HDIM * 4);
    size_t state_bytes = (ws + off) - state_base;
    float* he = (float*)alloc((size_t)NSEQ * HDIM * 4);
    int* nzb  = (int*)alloc(NSEQ * 4);

    float* out = (float*)d_out;
    float* ques_embed = out;
    float* text_rel   = out + (size_t)NSEQ * HDIM;

    const int rowoff[2] = {0, 6400};
    const int TT[2] = {20, 40};
    const int* toks[2] = {ques, hist};
    const int* lens[2] = {ques_len, hist_len};

    // ---- weight conversions ----
    conv_bf16_kernel<<<dim3(4, HDIM), 256, 0, stream>>>(Wc, ELMOD, Wcb, ELMOD, 0, ELMOD);
    for (int s = 0; s < 2; ++s) {
        const float* Wih0 = (const float*)d_in[10 + 6*s];
        const float* Whh0 = (const float*)d_in[11 + 6*s];
        const float* Wih1 = (const float*)d_in[13 + 6*s];
        const float* Whh1 = (const float*)d_in[14 + 6*s];
        conv_bf16_kernel<<<dim3(4, G4), 256, 0, stream>>>(Wih0, 812, Wih0b[s], XPAD, 0, XPAD);
        conv_bf16_kernel<<<dim3(2, G4), 256, 0, stream>>>(Whh0, HDIM, Whh0b[s], HDIM, 0, HDIM);
        conv_bf16_kernel<<<dim3(2, G4), 256, 0, stream>>>(Wih1, HDIM, Wcat[s], ELMOD, 0, HDIM);
        conv_bf16_kernel<<<dim3(2, G4), 256, 0, stream>>>(Whh1, HDIM, Wcat[s], ELMOD, HDIM, HDIM);
    }

    // ---- embeddings + input projections ----
    for (int s = 0; s < 2; ++s) {
        int Ntok = NSEQ * TT[s];
        ushort_t* XbS = Xb + (size_t)rowoff[s] * XPAD;
        emb_gather_kernel<<<Ntok, 128, 0, stream>>>(toks[s], w_emb, XbS);
        // Xb[:,300:812] = bf16(elmo[tok] @ Wc^T + bc)
        gemm_ff_kernel<<<dim3(HDIM/64, Ntok/64), 256, 0, stream>>>(
            nullptr, elmo, toks[s], ELMOD, Wcb, bc, XbS + EMBD, XPAD, ELMOD);
        // XP0 = bf16(X @ Wih0^T + b0)
        const float* b0 = (const float*)d_in[12 + 6*s];
        gemm_ff_kernel<<<dim3(G4/64, Ntok/64), 256, 0, stream>>>(
            XbS, nullptr, nullptr, XPAD, Wih0b[s], b0,
            XP0bf + (size_t)rowoff[s] * G4, G4, XPAD);
    }

    // ---- zero all recurrent state ----
    hipMemsetAsync(state_base, 0, state_bytes, stream);

    // ---- 41 pipelined supersteps ----
    for (int ss = 0; ss <= 40; ++ss) {
        int par = ss & 1;
        CellPack P;
        int nc = 0;
        for (int s = 0; s < 2; ++s) {
            int T = TT[s];
            const float* b1 = (const float*)d_in[15 + 6*s];
            if (ss < T) {  // layer-0 step t=ss
                Cell& c = P.cells[nc++];
                c.A = h0buf[s][par]; c.B = Whh0b[s];
                c.xp = XP0bf + ((size_t)rowoff[s] + ss) * G4;
                c.xpRowStride = T * G4;
                c.bias = nullptr;
                c.c = cbuf[s][0];
                c.hA = h0buf[s][par ^ 1]; c.strideHA = HDIM;
                c.hB = acat[s][par ^ 1];          // x-input for layer 1
                c.hlast = nullptr; c.lens = lens[s];
                c.t = ss; c.K = HDIM;
            }
            if (ss >= 1 && ss <= T) {  // layer-1 step t=ss-1
                Cell& c = P.cells[nc++];
                c.A = acat[s][par]; c.B = Wcat[s];
                c.xp = nullptr; c.xpRowStride = 0;
                c.bias = b1;
                c.c = cbuf[s][1];
                c.hA = acat[s][par ^ 1] + HDIM; c.strideHA = ELMOD;
                c.hB = nullptr;
                c.hlast = s ? he : ques_embed; c.lens = lens[s];
                c.t = ss - 1; c.K = ELMOD;
            }
        }
        if (nc == 0) continue;
        lstm_superstep_kernel<<<dim3(HDIM/16, NSEQ/64, nc), 256, 0, stream>>>(P);
    }

    // ---- expansion ----
    nz_kernel<<<NSEQ, 64, 0, stream>>>(he, nzb);
    expand_kernel<<<32000, 256, 0, stream>>>(he, nzb, text_rel);
}